// Round 9
// baseline (74.341 us; speedup 1.0000x reference)
//
#include <hip/hip_runtime.h>

// ECT: nh = x @ v -> bin -> histogram over (batch, bin, theta) -> cumsum over bins.
// batch is SORTED: each block owns (batch, theta-slice) exclusively; no global
// atomics, no workspace.
//
// R1: 8x unroll (latency)                 42 -> ~26 us
// R2: 4 thetas/thread (VMEM issue)        ~26 -> ~21 us
// R3: float4 chunk loads + ballot search  ~21 -> ~16 us
// R4/R5: occupancy 2x + exact banking     NEUTRAL x2 -> not occupancy-bound.
// R6: search-first + 3-deep pipeline      ~16 -> ~15 us
// R7: XCD swizzle + init overlap          NEUTRAL -> DS-atomic scatter floor.
// R8(this): exploit the data distribution: nh ~ N(0,1) and bins clamp at +-1,
//   so P(bin=0)=P(bin=127)~16.3% each -> 32.6% of all increments hit 2 bins.
//   Those are counted in per-thread VGPRs and merged with 1 atomic/thread at
//   the end, cutting DS bank-work ~32% IF the ds_add cost is bank-work-limited
//   (m136: conflict cost scales with bank accesses). If ds_add is issue-limited
//   (fixed cyc/wave-instr), this is neutral and the scatter roofline stands:
//   400K ds_add wave-instrs x ~17cyc / 256 CU ~ 11-13 us + ramp = measured.

constexpr int N_PTS    = 200000;
constexpr int T        = 128;   // num_thetas
constexpr int R        = 128;   // resolution
constexpr int B        = 64;    // batch_size
constexpr int TT       = 32;    // thetas per block (4 slices per batch)
constexpr int NTHREADS = 1024;
constexpr int TG       = 8;     // theta-groups per block (4 thetas each)
constexpr int PL       = NTHREADS / TG;     // 128 chunk-lanes per block
constexpr int SUBS     = NTHREADS / TT;     // 32 epilogue segs
constexpr int RCH      = R / SUBS;          // 4 rows per seg

__global__ __launch_bounds__(NTHREADS)
void FastEctLayer_73065983639654_kernel(const float* __restrict__ x,
                                        const float* __restrict__ v,
                                        const int*   __restrict__ batch,
                                        float*       __restrict__ out) {
    __shared__ uint4        hist4[R * TT / 4];   // 16 KiB, [bin][tl] as u32
    __shared__ unsigned int partial[SUBS * TT];  // 4 KiB, [seg][tl]
    __shared__ unsigned int grp[4 * TT];         // 512 B
    __shared__ int s_range[2];
    unsigned int* hist = (unsigned int*)hist4;

    const int tid  = threadIdx.x;
    const int wave = tid >> 6, lane = tid & 63;
    // XCD swizzle: sibling blocks of a batch differ by 64 ≡ 0 mod 8 -> same XCD L2.
    const int bat    = blockIdx.x & 63;
    const int theta0 = (blockIdx.x >> 6) * TT;

    if (wave < 2) {
        // 64-ary cooperative lower_bound (3 dependent probe rounds).
        const int val = bat + wave;
        int lo = 0, hi = N_PTS;
        while (lo < hi) {
            const int step = (hi - lo + 63) >> 6;
            const int pos  = lo + lane * step;
            const bool pred = (pos < hi) && (batch[pos] < val);
            const unsigned long long m = __ballot(pred);
            const int k = __popcll(m);
            if (k == 0) {
                hi = lo;
            } else {
                const int nlo = lo + (k - 1) * step + 1;
                hi = min(hi, lo + k * step);
                lo = nlo;
            }
        }
        if (lane == 0) s_range[wave] = lo;
    } else {
        // waves 2..15 own the hist init (vectorized, off the critical path)
        const uint4 z = {0u, 0u, 0u, 0u};
        for (int i = tid - 128; i < R * TT / 4; i += NTHREADS - 128) hist4[i] = z;
    }

    // 4 thetas/thread, diagonalized: tl_j = (4tg+j+pl) mod 32 -> per wave-instr
    // each bank hit exactly twice (2-way = free, m136); (tg,j) bijective.
    const int tg = tid & (TG - 1);
    const int pl = tid >> 3;
    int   tlj[4];
    float vv0[4], vv1[4], vv2[4];
#pragma unroll
    for (int j = 0; j < 4; ++j) {
        const int tl = (4 * tg + j + pl) & (TT - 1);
        tlj[j] = tl;
        vv0[j] = v[0 * T + theta0 + tl] * 64.0f;   // pre-scaled: bin_f = dot + 64
        vv1[j] = v[1 * T + theta0 + tl] * 64.0f;
        vv2[j] = v[2 * T + theta0 + tl] * 64.0f;
    }

    __syncthreads();
    const int start = s_range[0];
    const int end   = s_range[1];

    const int a0      = start & ~3;
    const int nchunks = (end - a0 + 3) >> 2;
    const float4* __restrict__ X4 = (const float4*)x;
    const int cbase = (a0 >> 2) * 3;

    // register accumulators for the two clamped (hot) bins
    unsigned int c0[4]   = {0u, 0u, 0u, 0u};
    unsigned int c127[4] = {0u, 0u, 0u, 0u};

    auto pair = [&](float pxi, float pyi, float pzi, int j) {
        const float bf = fmaf(pxi, vv0[j], fmaf(pyi, vv1[j], fmaf(pzi, vv2[j], 64.0f)));
        const bool lo = bf < 1.0f;          // clamp -> bin 0
        const bool hi = bf >= 127.0f;       // clamp -> bin 127
        c0[j]   += lo;
        c127[j] += hi;
        if (!lo && !hi) {                   // ~67% of lanes active
            const int bin = (int)bf;        // 1..126, trunc==floor
            atomicAdd(&hist[(bin << 5) + tlj[j]], 1u);
        }
    };

    auto process4 = [&](int pbase, float4 f0, float4 f1, float4 f2) {
        const float px[4] = {f0.x, f0.w, f1.z, f2.y};
        const float py[4] = {f0.y, f1.x, f1.w, f2.z};
        const float pz[4] = {f0.z, f1.y, f2.x, f2.w};
        if (pbase >= start && pbase + 3 < end) {
#pragma unroll
            for (int i = 0; i < 4; ++i)
#pragma unroll
                for (int j = 0; j < 4; ++j) pair(px[i], py[i], pz[i], j);
        } else {
#pragma unroll
            for (int i = 0; i < 4; ++i) {
                const int p = pbase + i;
                if (p >= start && p < end)
#pragma unroll
                    for (int j = 0; j < 4; ++j) pair(px[i], py[i], pz[i], j);
            }
        }
    };

    // 3-deep software-pipelined chunk loop (1-2 chunks of VMEM in flight)
    int c = pl;
    float4 A0, A1, A2, B0, B1, B2;
    bool haveA = (c < nchunks);
    if (haveA) { A0 = X4[cbase + 3*c]; A1 = X4[cbase + 3*c + 1]; A2 = X4[cbase + 3*c + 2]; }
    bool haveB = (c + PL < nchunks);
    if (haveB) { B0 = X4[cbase + 3*(c+PL)]; B1 = X4[cbase + 3*(c+PL) + 1]; B2 = X4[cbase + 3*(c+PL) + 2]; }
    while (haveA) {
        const int cn = c + 2 * PL;
        const bool haveC = (cn < nchunks);
        float4 C0, C1, C2;
        if (haveC) { C0 = X4[cbase + 3*cn]; C1 = X4[cbase + 3*cn + 1]; C2 = X4[cbase + 3*cn + 2]; }
        process4(a0 + 4 * c, A0, A1, A2);
        A0 = B0; A1 = B1; A2 = B2; haveA = haveB;
        B0 = C0; B1 = C1; B2 = C2; haveB = haveC;
        c += PL;
    }

    // merge hot-bin register counts: 8 atomics/thread = 128 wave-instrs/block
    // (vs ~512 saved in the main loop's lane-work)
#pragma unroll
    for (int j = 0; j < 4; ++j) {
        atomicAdd(&hist[tlj[j]],              c0[j]);    // bin 0
        atomicAdd(&hist[(127 << 5) + tlj[j]], c127[j]);  // bin 127
    }

    __syncthreads();

    // cumsum over r: seg owns RCH=4 rows; two-level (4x8) scan over 32 segs.
    const int tl  = tid & (TT - 1);
    const int seg = tid >> 5;
    const int r0  = seg * RCH;
    unsigned int csum = 0;
#pragma unroll
    for (int r = r0; r < r0 + RCH; ++r) csum += hist[(r << 5) + tl];
    partial[seg * TT + tl] = csum;
    __syncthreads();

    if (tid < 4 * TT) {
        const int g = tid >> 5;
        unsigned int s = 0;
#pragma unroll
        for (int k = 0; k < 8; ++k) s += partial[(g * 8 + k) * TT + tl];
        grp[g * TT + tl] = s;
    }
    __syncthreads();

    unsigned int run = 0;
    const int g = seg >> 3;
    for (int gg = 0; gg < g; ++gg)        run += grp[gg * TT + tl];
    for (int s2 = g * 8; s2 < seg; ++s2)  run += partial[s2 * TT + tl];
#pragma unroll
    for (int r = r0; r < r0 + RCH; ++r) {
        run += hist[(r << 5) + tl];
        out[((size_t)bat * R + r) * T + theta0 + tl] = (float)run;  // exact in f32
    }
}

extern "C" void kernel_launch(void* const* d_in, const int* in_sizes, int n_in,
                              void* d_out, int out_size, void* d_ws, size_t ws_size,
                              hipStream_t stream) {
    const float* x     = (const float*)d_in[0];
    const float* v     = (const float*)d_in[1];
    const int*   batch = (const int*)d_in[2];
    float*       out   = (float*)d_out;

    dim3 grid(B * 4);   // 256 blocks = 1 per CU; bat = bIdx&63 (XCD-swizzled)
    dim3 block(NTHREADS);
    hipLaunchKernelGGL(FastEctLayer_73065983639654_kernel, grid, block, 0, stream,
                       x, v, batch, out);
}

// Round 10
// 70.096 us; speedup vs baseline: 1.0606x; 1.0606x over previous
//
#include <hip/hip_runtime.h>

// ECT: nh = x @ v -> bin -> histogram over (batch, bin, theta) -> cumsum over bins.
// batch is SORTED: each block owns (batch, theta-slice) exclusively; no global
// atomics, no workspace.
//
// Trajectory (bench dur_us; kernel ~= bench - 55.5 us harness overhead):
// R1: 8x unroll (latency)                 97.7 -> 82.0
// R2: 4 thetas/thread (VMEM issue)        82.0 -> 77.3
// R3: float4 chunks + ballot search       77.3 -> 71.8
// R4/R5: occupancy 2x + exact banking     NEUTRAL x2 -> not occupancy-bound
// R6: search-first + 3-deep pipeline      71.8 -> 70.7
// R7: XCD swizzle + init overlap          NEUTRAL (70.5)
// R9: hot-bin VGPR accumulation           REGRESSED (74.3) -> ds_add is
//     ISSUE-LIMITED per wave-instr (~17 cyc), lane-masking saves nothing.
// R10(this): revert to R8 best. STRUCTURAL FLOOR: 25.6M increments / 64 lanes
//   = 400K ds_add wave-instrs (irreducible: destinations are data-random so no
//   packing can combine them; no per-lane dynamic register indexing on gfx950)
//   x ~17 cyc / 256 CU ~ 11 us + ~2 us VALU/ramp + ~1.5 us epilogue ~ 15 us
//   kernel = measured. DS-atomic scatter roofline.

constexpr int N_PTS    = 200000;
constexpr int T        = 128;   // num_thetas
constexpr int R        = 128;   // resolution
constexpr int B        = 64;    // batch_size
constexpr int TT       = 32;    // thetas per block (4 slices per batch)
constexpr int NTHREADS = 1024;
constexpr int TG       = 8;     // theta-groups per block (4 thetas each)
constexpr int PL       = NTHREADS / TG;     // 128 chunk-lanes per block
constexpr int SUBS     = NTHREADS / TT;     // 32 epilogue segs
constexpr int RCH      = R / SUBS;          // 4 rows per seg

__global__ __launch_bounds__(NTHREADS)
void FastEctLayer_73065983639654_kernel(const float* __restrict__ x,
                                        const float* __restrict__ v,
                                        const int*   __restrict__ batch,
                                        float*       __restrict__ out) {
    __shared__ uint4        hist4[R * TT / 4];   // 16 KiB, [bin][tl] as u32
    __shared__ unsigned int partial[SUBS * TT];  // 4 KiB, [seg][tl]
    __shared__ unsigned int grp[4 * TT];         // 512 B
    __shared__ int s_range[2];
    unsigned int* hist = (unsigned int*)hist4;

    const int tid  = threadIdx.x;
    const int wave = tid >> 6, lane = tid & 63;
    // XCD swizzle: sibling blocks of a batch differ by 64 ≡ 0 mod 8 -> same XCD L2.
    const int bat    = blockIdx.x & 63;
    const int theta0 = (blockIdx.x >> 6) * TT;

    if (wave < 2) {
        // 64-ary cooperative lower_bound (3 dependent probe rounds).
        // wave 0 -> start, wave 1 -> end; runs under waves 2..15's init.
        const int val = bat + wave;
        int lo = 0, hi = N_PTS;
        while (lo < hi) {
            const int step = (hi - lo + 63) >> 6;
            const int pos  = lo + lane * step;
            const bool pred = (pos < hi) && (batch[pos] < val);
            const unsigned long long m = __ballot(pred);
            const int k = __popcll(m);
            if (k == 0) {
                hi = lo;
            } else {
                const int nlo = lo + (k - 1) * step + 1;
                hi = min(hi, lo + k * step);
                lo = nlo;
            }
        }
        if (lane == 0) s_range[wave] = lo;
    } else {
        // waves 2..15 own the hist init (vectorized, off the critical path)
        const uint4 z = {0u, 0u, 0u, 0u};
        for (int i = tid - 128; i < R * TT / 4; i += NTHREADS - 128) hist4[i] = z;
    }

    // 4 thetas/thread, diagonalized: tl_j = (4tg+j+pl) mod 32 -> per wave-instr
    // each bank hit exactly twice (2-way = free, m136); (tg,j) bijective.
    const int tg = tid & (TG - 1);
    const int pl = tid >> 3;
    int   tlj[4];
    float vv0[4], vv1[4], vv2[4];
#pragma unroll
    for (int j = 0; j < 4; ++j) {
        const int tl = (4 * tg + j + pl) & (TT - 1);
        tlj[j] = tl;
        vv0[j] = v[0 * T + theta0 + tl] * 64.0f;   // pre-scaled: bin_f = dot + 64
        vv1[j] = v[1 * T + theta0 + tl] * 64.0f;
        vv2[j] = v[2 * T + theta0 + tl] * 64.0f;
    }

    __syncthreads();
    const int start = s_range[0];
    const int end   = s_range[1];

    // chunk-of-4 points, 16B-aligned float4 loads; <=2 points past `end`
    // predicated out (next batch's points; end==N is 4-aligned with a0).
    const int a0      = start & ~3;
    const int nchunks = (end - a0 + 3) >> 2;
    const float4* __restrict__ X4 = (const float4*)x;
    const int cbase = (a0 >> 2) * 3;

    auto process4 = [&](int pbase, float4 f0, float4 f1, float4 f2) {
        const float px[4] = {f0.x, f0.w, f1.z, f2.y};
        const float py[4] = {f0.y, f1.x, f1.w, f2.z};
        const float pz[4] = {f0.z, f1.y, f2.x, f2.w};
        if (pbase >= start && pbase + 3 < end) {
#pragma unroll
            for (int i = 0; i < 4; ++i) {
#pragma unroll
                for (int j = 0; j < 4; ++j) {
                    const float bf = fmaf(px[i], vv0[j], fmaf(py[i], vv1[j],
                                     fmaf(pz[i], vv2[j], 64.0f)));
                    int bin = (int)bf;
                    bin = min(max(bin, 0), R - 1);          // v_med3_i32
                    atomicAdd(&hist[(bin << 5) + tlj[j]], 1u);  // ds_add, no return
                }
            }
        } else {
#pragma unroll
            for (int i = 0; i < 4; ++i) {
                const int p = pbase + i;
                if (p >= start && p < end) {
#pragma unroll
                    for (int j = 0; j < 4; ++j) {
                        const float bf = fmaf(px[i], vv0[j], fmaf(py[i], vv1[j],
                                         fmaf(pz[i], vv2[j], 64.0f)));
                        int bin = (int)bf;
                        bin = min(max(bin, 0), R - 1);
                        atomicAdd(&hist[(bin << 5) + tlj[j]], 1u);
                    }
                }
            }
        }
    };

    // 3-deep software-pipelined chunk loop (1-2 chunks of VMEM in flight)
    int c = pl;
    float4 A0, A1, A2, B0, B1, B2;
    bool haveA = (c < nchunks);
    if (haveA) { A0 = X4[cbase + 3*c]; A1 = X4[cbase + 3*c + 1]; A2 = X4[cbase + 3*c + 2]; }
    bool haveB = (c + PL < nchunks);
    if (haveB) { B0 = X4[cbase + 3*(c+PL)]; B1 = X4[cbase + 3*(c+PL) + 1]; B2 = X4[cbase + 3*(c+PL) + 2]; }
    while (haveA) {
        const int cn = c + 2 * PL;
        const bool haveC = (cn < nchunks);
        float4 C0, C1, C2;
        if (haveC) { C0 = X4[cbase + 3*cn]; C1 = X4[cbase + 3*cn + 1]; C2 = X4[cbase + 3*cn + 2]; }
        process4(a0 + 4 * c, A0, A1, A2);
        A0 = B0; A1 = B1; A2 = B2; haveA = haveB;
        B0 = C0; B1 = C1; B2 = C2; haveB = haveC;
        c += PL;
    }

    __syncthreads();

    // cumsum over r: seg owns RCH=4 rows; two-level (4x8) scan over 32 segs.
    const int tl  = tid & (TT - 1);
    const int seg = tid >> 5;
    const int r0  = seg * RCH;
    unsigned int csum = 0;
#pragma unroll
    for (int r = r0; r < r0 + RCH; ++r) csum += hist[(r << 5) + tl];
    partial[seg * TT + tl] = csum;
    __syncthreads();

    if (tid < 4 * TT) {
        const int g = tid >> 5;
        unsigned int s = 0;
#pragma unroll
        for (int k = 0; k < 8; ++k) s += partial[(g * 8 + k) * TT + tl];
        grp[g * TT + tl] = s;
    }
    __syncthreads();

    unsigned int run = 0;
    const int g = seg >> 3;
    for (int gg = 0; gg < g; ++gg)        run += grp[gg * TT + tl];
    for (int s2 = g * 8; s2 < seg; ++s2)  run += partial[s2 * TT + tl];
#pragma unroll
    for (int r = r0; r < r0 + RCH; ++r) {
        run += hist[(r << 5) + tl];
        out[((size_t)bat * R + r) * T + theta0 + tl] = (float)run;  // exact in f32
    }
}

extern "C" void kernel_launch(void* const* d_in, const int* in_sizes, int n_in,
                              void* d_out, int out_size, void* d_ws, size_t ws_size,
                              hipStream_t stream) {
    const float* x     = (const float*)d_in[0];
    const float* v     = (const float*)d_in[1];
    const int*   batch = (const int*)d_in[2];
    float*       out   = (float*)d_out;

    dim3 grid(B * 4);   // 256 blocks = 1 per CU; bat = bIdx&63 (XCD-swizzled)
    dim3 block(NTHREADS);
    hipLaunchKernelGGL(FastEctLayer_73065983639654_kernel, grid, block, 0, stream,
                       x, v, batch, out);
}